// Round 1
// baseline (1731.217 us; speedup 1.0000x reference)
//
#include <hip/hip_runtime.h>
#include <math.h>

#define NROWS 1048576
#define D 256
#define C 65
#define EPSV 1e-8f

// --- Pre-kernel: weight norms -> d_ws (65 floats). One wave per cluster. ---
__global__ void wn_kernel(const float* __restrict__ w, float* __restrict__ wn) {
    int c = blockIdx.x;          // 0..64
    int l = threadIdx.x;         // 0..63
    float s = 0.f;
    #pragma unroll
    for (int d = l; d < D; d += 64) {
        float v = w[c * D + d];
        s = fmaf(v, v, s);
    }
    #pragma unroll
    for (int off = 32; off; off >>= 1) s += __shfl_down(s, off);
    if (l == 0) wn[c] = sqrtf(s);
}

// --- Main kernel: one thread per row. ---
// Inner loop: 65 accumulators in VGPRs, weights via wave-uniform (scalar) loads,
// x via per-lane float4 loads (each 16-float chunk = one 64B line per lane).
__global__ __launch_bounds__(256) void scluster_kernel(
    const float* __restrict__ x, const float* __restrict__ w,
    const float* __restrict__ wn, float* __restrict__ out)
{
    const int row = blockIdx.x * 256 + threadIdx.x;
    const float* __restrict__ xr = x + (size_t)row * D;

    float acc[C];
    #pragma unroll
    for (int c = 0; c < C; ++c) acc[c] = 0.f;
    float xn2 = 0.f;

    // d-chunk loop kept rolled (16 iters); c/j loops fully unrolled.
    for (int d0 = 0; d0 < D; d0 += 16) {
        float xv[16];
        #pragma unroll
        for (int j = 0; j < 16; j += 4) {
            float4 v = *reinterpret_cast<const float4*>(xr + d0 + j);
            xv[j] = v.x; xv[j + 1] = v.y; xv[j + 2] = v.z; xv[j + 3] = v.w;
        }
        #pragma unroll
        for (int j = 0; j < 16; ++j) xn2 = fmaf(xv[j], xv[j], xn2);
        #pragma unroll
        for (int c = 0; c < C; ++c) {
            float a = acc[c];
            #pragma unroll
            for (int j = 0; j < 16; ++j)
                a = fmaf(w[c * D + d0 + j], xv[j], a);   // uniform addr -> s_load
            acc[c] = a;
        }
    }

    // cosine sim (reuse acc[] as sim[] to save VGPRs)
    const float xn = sqrtf(xn2);
    float m = -INFINITY;
    #pragma unroll
    for (int c = 0; c < C; ++c) {
        float denom = fmaxf(xn * wn[c], EPSV);           // wn: uniform -> s_load
        float s = acc[c] * __builtin_amdgcn_rcpf(denom);
        acc[c] = s;
        m = fmaxf(m, s);
    }
    // softmax(sim) == softmax(1 + sim) == softmax((1+sim)^1.0) == reference
    float sum = 0.f;
    #pragma unroll
    for (int c = 0; c < C; ++c) {
        float e = __expf(acc[c] - m);
        acc[c] = e;
        sum += e;
    }
    const float rs = __builtin_amdgcn_rcpf(sum);

    float* __restrict__ orow = out + (size_t)row * C;
    #pragma unroll
    for (int c = 0; c < C; ++c) orow[c] = acc[c] * rs;
}

extern "C" void kernel_launch(void* const* d_in, const int* in_sizes, int n_in,
                              void* d_out, int out_size, void* d_ws, size_t ws_size,
                              hipStream_t stream) {
    const float* x = (const float*)d_in[0];
    const float* w = (const float*)d_in[1];
    float* out = (float*)d_out;
    float* wn = (float*)d_ws;

    wn_kernel<<<C, 64, 0, stream>>>(w, wn);
    scluster_kernel<<<NROWS / 256, 256, 0, stream>>>(x, w, wn, out);
}

// Round 2
// 779.535 us; speedup vs baseline: 2.2208x; 2.2208x over previous
//
#include <hip/hip_runtime.h>
#include <math.h>

#define NROWS 1048576
#define D 256
#define C 65
#define EPSV 1e-8f

// --- Pre-kernel: weight norms -> d_ws (65 floats). One wave per cluster. ---
__global__ void wn_kernel(const float* __restrict__ w, float* __restrict__ wn) {
    int c = blockIdx.x;          // 0..64
    int l = threadIdx.x;         // 0..63
    float s = 0.f;
    #pragma unroll
    for (int d = l; d < D; d += 64) {
        float v = w[c * D + d];
        s = fmaf(v, v, s);
    }
    #pragma unroll
    for (int off = 32; off; off >>= 1) s += __shfl_down(s, off);
    if (l == 0) wn[c] = sqrtf(s);
}

// --- Main kernel: one thread per row; w staged in LDS (2 phases of [C][128]).
// Inner loop: broadcast ds_read_b128 (base + imm offset, compile-time c) + v_fmac.
// Output: softmax in regs, then coalesced stores via LDS transpose restage.
__global__ __launch_bounds__(256, 4) void scluster_kernel(
    const float* __restrict__ x, const float* __restrict__ w,
    const float* __restrict__ wn, float* __restrict__ out)
{
    __shared__ float wbuf[C * 128];          // 33,280 B (also reused as store-staging)
    const int tid = threadIdx.x;
    const int row = blockIdx.x * 256 + tid;
    const float* __restrict__ xr = x + (size_t)row * D;

    float acc[C];
    #pragma unroll
    for (int c = 0; c < C; ++c) acc[c] = 0.f;
    float xn2 = 0.f;

    #pragma unroll 1
    for (int p = 0; p < 2; ++p) {
        // stage w[:, p*128 .. p*128+127] -> wbuf[C][128]  (coalesced float4)
        #pragma unroll 1
        for (int i = tid; i < C * 32; i += 256) {
            const int c  = i >> 5;
            const int j4 = (i & 31) << 2;
            *reinterpret_cast<float4*>(&wbuf[c * 128 + j4]) =
                *reinterpret_cast<const float4*>(&w[c * 256 + p * 128 + j4]);
        }
        __syncthreads();

        #pragma unroll 1
        for (int d0 = 0; d0 < 128; d0 += 8) {
            const float4 a = *reinterpret_cast<const float4*>(xr + p * 128 + d0);
            const float4 b = *reinterpret_cast<const float4*>(xr + p * 128 + d0 + 4);
            const float xv0 = a.x, xv1 = a.y, xv2 = a.z, xv3 = a.w;
            const float xv4 = b.x, xv5 = b.y, xv6 = b.z, xv7 = b.w;
            xn2 = fmaf(xv0, xv0, xn2); xn2 = fmaf(xv1, xv1, xn2);
            xn2 = fmaf(xv2, xv2, xn2); xn2 = fmaf(xv3, xv3, xn2);
            xn2 = fmaf(xv4, xv4, xn2); xn2 = fmaf(xv5, xv5, xn2);
            xn2 = fmaf(xv6, xv6, xn2); xn2 = fmaf(xv7, xv7, xn2);
            #pragma unroll
            for (int c = 0; c < C; ++c) {
                const float4 w0 = *reinterpret_cast<const float4*>(&wbuf[c * 128 + d0]);
                const float4 w1 = *reinterpret_cast<const float4*>(&wbuf[c * 128 + d0 + 4]);
                float t = acc[c];
                t = fmaf(w0.x, xv0, t); t = fmaf(w0.y, xv1, t);
                t = fmaf(w0.z, xv2, t); t = fmaf(w0.w, xv3, t);
                t = fmaf(w1.x, xv4, t); t = fmaf(w1.y, xv5, t);
                t = fmaf(w1.z, xv6, t); t = fmaf(w1.w, xv7, t);
                acc[c] = t;
            }
        }
        __syncthreads();   // before next-phase restage / store restage
    }

    // --- cosine sim + softmax, fully in registers ---
    const float xn = sqrtf(xn2);
    float m = -INFINITY;
    #pragma unroll
    for (int c = 0; c < C; ++c) {
        const float denom = fmaxf(xn * wn[c], EPSV);
        const float s = acc[c] * __builtin_amdgcn_rcpf(denom);
        acc[c] = s;
        m = fmaxf(m, s);
    }
    float sum = 0.f;
    #pragma unroll
    for (int c = 0; c < C; ++c) {
        const float e = __expf(acc[c] - m);
        acc[c] = e;
        sum += e;
    }
    const float rs = __builtin_amdgcn_rcpf(sum);
    #pragma unroll
    for (int c = 0; c < C; ++c) acc[c] *= rs;

    // --- coalesced store via LDS restage: waves {0,1} then {2,3} ---
    const int wv = tid >> 6;
    const int lane = tid & 63;
    float* obuf = wbuf;                      // [2][64*C] = 33,280 B, reused

    auto emit = [&](int slot) {
        float* tile = obuf + slot * (64 * C);
        // scatter own row into LDS: banks (lane*65+c)%32 = (lane+c)%32 -> 2/bank, free
        #pragma unroll
        for (int c = 0; c < C; ++c) tile[lane * C + c] = acc[c];
        asm volatile("s_waitcnt lgkmcnt(0)" ::: "memory");  // same-wave write->read order
        const size_t gbase = ((size_t)blockIdx.x * 256 + (size_t)wv * 64) * C;
        // 64*65 = 4160 dwords: 16 float4/lane + 1 dword/lane, all 16B-aligned
        #pragma unroll
        for (int k = 0; k < 16; ++k) {
            const float4 v = *reinterpret_cast<const float4*>(&tile[k * 256 + lane * 4]);
            *reinterpret_cast<float4*>(&out[gbase + k * 256 + lane * 4]) = v;
        }
        out[gbase + 4096 + lane] = tile[4096 + lane];
    };

    if (wv < 2) emit(wv);          // waves 0,1 use the two LDS slots
    __syncthreads();
    if (wv >= 2) emit(wv - 2);     // then waves 2,3
}

extern "C" void kernel_launch(void* const* d_in, const int* in_sizes, int n_in,
                              void* d_out, int out_size, void* d_ws, size_t ws_size,
                              hipStream_t stream) {
    const float* x = (const float*)d_in[0];
    const float* w = (const float*)d_in[1];
    float* out = (float*)d_out;
    float* wn = (float*)d_ws;

    wn_kernel<<<C, 64, 0, stream>>>(w, wn);
    scluster_kernel<<<NROWS / 256, 256, 0, stream>>>(x, w, wn, out);
}